// Round 2
// baseline (231.764 us; speedup 1.0000x reference)
//
#include <hip/hip_runtime.h>

typedef _Float16 h2 __attribute__((ext_vector_type(2)));

// ---- DPP wave-64 inclusive sum (VALU pipe): full sum lands in lane 63 ----
template <int CTRL>
__device__ __forceinline__ float dpp_stage(float v) {
    int x = __builtin_amdgcn_update_dpp(0, __float_as_int(v), CTRL, 0xf, 0xf, true);
    return v + __int_as_float(x);
}
__device__ __forceinline__ float wave_sum(float v) {
    v = dpp_stage<0x111>(v);  // row_shr:1
    v = dpp_stage<0x112>(v);  // row_shr:2
    v = dpp_stage<0x114>(v);  // row_shr:4
    v = dpp_stage<0x118>(v);  // row_shr:8
    v = dpp_stage<0x142>(v);  // row_bcast:15
    v = dpp_stage<0x143>(v);  // row_bcast:31
    return v;                 // lane 63 holds the full sum
}
__device__ __forceinline__ float bcast63(float v) {
    return __int_as_float(__builtin_amdgcn_readlane(__float_as_int(v), 63));
}
__device__ __forceinline__ h2 mid2(h2 lo, h2 hi) {
    // (lo.y, hi.x) in one whole-register op: v_alignbit_b32
    int r = __builtin_amdgcn_alignbit(__builtin_bit_cast(int, hi),
                                      __builtin_bit_cast(int, lo), 16);
    return __builtin_bit_cast(h2, r);
}
__device__ __forceinline__ h2 pkrtz(float a, float b) {
    return __builtin_bit_cast(h2, __builtin_amdgcn_cvt_pkrtz(a, b));
}

// Compiler-level memory fence: emits NO instructions, but forbids LLVM from
// reordering/hoisting/sinking LDS loads & stores across it. Required because
// lane-local alias analysis can PROVE bp[0] etc. never alias the bp[55..59]
// stores and would otherwise hoist the neighbor-column loads out of the
// 8-iteration loop (stale-neighbor bug, absmax ~88 in round 1). The hardware
// DS pipe is in-order per wave, so program order alone is sufficient — we just
// have to make the compiler keep program order.
#define MEMFENCE() asm volatile("" ::: "memory")

// one window column (dx,dy in 0..2): LDS dword reads from ONE base VGPR via
// offset immediates, 4 alignbit, 12 v_pk_fma_f16 covering all 4 output
// z-pairs of this thread.
#define COL(DX, DY) {                                                          \
    const int o = 5 * (10 * (DX) + (DY));                                      \
    h2 D0 = bp[o + 0], D1 = bp[o + 1], D2 = bp[o + 2], D3 = bp[o + 3],         \
       D4 = bp[o + 4];                                                         \
    h2 M0 = mid2(D0, D1), M1 = mid2(D1, D2), M2 = mid2(D2, D3),                \
       M3 = mid2(D3, D4);                                                      \
    const int tA = ((DX) * 3 + (DY)) * 3;                                      \
    dd0 = __builtin_elementwise_fma(D0, w[tA][0], dd0);                        \
    dd1 = __builtin_elementwise_fma(D1, w[tA][1], dd1);                        \
    dd2 = __builtin_elementwise_fma(D2, w[tA][2], dd2);                        \
    dd3 = __builtin_elementwise_fma(D3, w[tA][3], dd3);                        \
    dd0 = __builtin_elementwise_fma(M0, w[tA + 1][0], dd0);                    \
    dd1 = __builtin_elementwise_fma(M1, w[tA + 1][1], dd1);                    \
    dd2 = __builtin_elementwise_fma(M2, w[tA + 1][2], dd2);                    \
    dd3 = __builtin_elementwise_fma(M3, w[tA + 1][3], dd3);                    \
    dd0 = __builtin_elementwise_fma(D1, w[tA + 2][0], dd0);                    \
    dd1 = __builtin_elementwise_fma(D2, w[tA + 2][1], dd1);                    \
    dd2 = __builtin_elementwise_fma(D3, w[tA + 2][2], dd2);                    \
    dd3 = __builtin_elementwise_fma(D4, w[tA + 2][3], dd3); }

// normalized-dot correction + bias + silu + residual for one output
#define OUTK(CK, DDF, SWK, BK, RK) {                                           \
    float u = fmaf(fmaf(SWK, nmean, DDF), istd, BK);                           \
    CK += RK * (u * __builtin_amdgcn_rcpf(1.f + __expf(-u))); }

__global__ __launch_bounds__(64)
void gridnet_kernel(const float* __restrict__ W,
                    const float* __restrict__ Bias,
                    const float* __restrict__ Rs,
                    const float* __restrict__ X,
                    float* __restrict__ Y,
                    int n_batch)
{
    // single buffer: 10x10 columns x 10 z-halves = 2 KB. One wave per block =>
    // LDS ops complete in program order; with the MEMFENCEs pinning compiler
    // order, no ping-pong and ZERO barriers are needed.
    __shared__ __align__(16) h2 buf[500];

    const int tid = threadIdx.x;    // 0..63, one wave
    const int lx  = tid >> 3;       // 0..7
    const int ly  = tid & 7;

    // chunked XCD swizzle: XCD = bid%8 gets a contiguous 1/8 chunk of logical
    // block ids -> all 16 batch-sharers of a weight tile hit the same L2.
    const int nwg = (int)gridDim.x;           // 512*n_batch, divisible by 8
    const int b0  = (int)blockIdx.x;
    const int bid = (b0 & 7) * (nwg >> 3) + (b0 >> 3);

    const int r     = bid / n_batch;          // spatial block 0..511
    const int batch = bid - r * n_batch;
    const int gm0 = (r >> 6) << 3;
    const int gn0 = ((r >> 3) & 7) << 3;
    const int gk0 = (r & 7) << 3;

    const float* xb = X + ((size_t)batch << 18);

    // -------- stage: each lane packs 1-2 whole z-columns; stats on rounded --
    float s_all = 0.f, q_all = 0.f, s_int = 0.f, q_int = 0.f;
    #pragma unroll 1
    for (int c = tid; c < 100; c += 64) {
        int x = c / 10, y = c - (c / 10) * 10;   // padded coords 0..9
        int m = gm0 + x - 1, n = gn0 + y - 1;
        bool row_ok = ((unsigned)m < 64u) & ((unsigned)n < 64u);
        float4 fa = {0.f, 0.f, 0.f, 0.f}, fb = {0.f, 0.f, 0.f, 0.f};
        float vz0 = 0.f, vz9 = 0.f;
        if (row_ok) {
            const float* rp = xb + (m * 4096 + n * 64);
            fa = *(const float4*)(rp + gk0);          // z = 1..4
            fb = *(const float4*)(rp + gk0 + 4);      // z = 5..8
            if (gk0 > 0)  vz0 = rp[gk0 - 1];          // uniform branches
            if (gk0 < 56) vz9 = rp[gk0 + 8];
        }
        h2 d0 = pkrtz(vz0, fa.x), d1 = pkrtz(fa.y, fa.z), d2 = pkrtz(fa.w, fb.x),
           d3 = pkrtz(fb.y, fb.z), d4 = pkrtz(fb.w, vz9);
        buf[c * 5 + 0] = d0; buf[c * 5 + 1] = d1; buf[c * 5 + 2] = d2;
        buf[c * 5 + 3] = d3; buf[c * 5 + 4] = d4;
        // stats over the f16-rounded values the dot will see
        float t0 = (float)d0.x, t1 = (float)d0.y, t2 = (float)d1.x,
              t3 = (float)d1.y, t4 = (float)d2.x, t5 = (float)d2.y,
              t6 = (float)d3.x, t7 = (float)d3.y, t8 = (float)d4.x,
              t9 = (float)d4.y;
        float s8 = t1 + t2 + t3 + t4 + t5 + t6 + t7 + t8;
        float q8 = t1*t1 + t2*t2 + t3*t3 + t4*t4 + t5*t5 + t6*t6 + t7*t7 + t8*t8;
        s_all += s8 + t0 + t9;
        q_all += q8 + t0*t0 + t9*t9;
        bool inter = ((unsigned)(x - 1) < 8u) & ((unsigned)(y - 1) < 8u);
        if (inter) { s_int += s8; q_int += q8; }
    }
    MEMFENCE();   // staging writes stay above everything below

    // -------- per-thread params: 27 taps x 8 k packed to 108 h2 regs --------
    const int gm = gm0 + lx, gn = gn0 + ly;
    const size_t ofs = ((size_t)gm << 12) + (gn << 6) + gk0;
    h2 w[27][4];
    float sw0=0.f, sw1=0.f, sw2=0.f, sw3=0.f, sw4=0.f, sw5=0.f, sw6=0.f, sw7=0.f;
    #pragma unroll
    for (int t = 0; t < 27; ++t) {
        const float* wp = W + ((size_t)t << 18) + ofs;
        float4 fa = *(const float4*)(wp);
        float4 fb = *(const float4*)(wp + 4);
        w[t][0] = pkrtz(fa.x, fa.y); w[t][1] = pkrtz(fa.z, fa.w);
        w[t][2] = pkrtz(fb.x, fb.y); w[t][3] = pkrtz(fb.z, fb.w);
        sw0 += fa.x; sw1 += fa.y; sw2 += fa.z; sw3 += fa.w;
        sw4 += fb.x; sw5 += fb.y; sw6 += fb.z; sw7 += fb.w;
    }
    float4 ba = *(const float4*)(Bias + ofs), bb = *(const float4*)(Bias + ofs + 4);
    float4 ra = *(const float4*)(Rs + ofs),   rb = *(const float4*)(Rs + ofs + 4);

    // -------- one-time block stats: DPP + readlane only (single wave) -------
    float S_all = bcast63(wave_sum(s_all));
    float Q_all = bcast63(wave_sum(q_all));
    float Si    = bcast63(wave_sum(s_int));
    float Qi    = bcast63(wave_sum(q_int));
    const float halo_s = S_all - Si;
    const float halo_q = Q_all - Qi;

    // -------- own column initial state (rounded values from LDS) ------------
    h2* bp = &buf[5 * (lx * 10 + ly)];     // window corner; own col = +55 dwords
    h2 e0 = bp[55], e1 = bp[56], e2 = bp[57], e3 = bp[58], e4 = bp[59];
    float z0f = (float)e0.x, z9f = (float)e4.y;       // frozen z-halo halves
    float c1 = (float)e0.y, c2 = (float)e1.x, c3 = (float)e1.y, c4 = (float)e2.x,
          c5 = (float)e2.y, c6 = (float)e3.x, c7 = (float)e3.y, c8 = (float)e4.x;

    const float inv_n = 1.0f / 1000.0f;

    #pragma unroll 1
    for (int it = 0; it < 8; ++it) {
        float mean  = (halo_s + Si) * inv_n;
        float qmean = (halo_q + Qi) * inv_n;
        float istd  = rsqrtf(qmean - mean * mean + 1e-5f);
        float nmean = -mean;

        h2 dd0 = { (_Float16)0.f, (_Float16)0.f };
        h2 dd1 = dd0, dd2 = dd0, dd3 = dd0;
        COL(0,0) COL(0,1) COL(0,2)
        COL(1,0) COL(1,1) COL(1,2)
        COL(2,0) COL(2,1) COL(2,2)

        MEMFENCE();  // all 27 column reads issue before the stores below

        OUTK(c1, (float)dd0.x, sw0, ba.x, ra.x)
        OUTK(c2, (float)dd0.y, sw1, ba.y, ra.y)
        OUTK(c3, (float)dd1.x, sw2, ba.z, ra.z)
        OUTK(c4, (float)dd1.y, sw3, ba.w, ra.w)
        OUTK(c5, (float)dd2.x, sw4, bb.x, rb.x)
        OUTK(c6, (float)dd2.y, sw5, bb.y, rb.y)
        OUTK(c7, (float)dd3.x, sw6, bb.z, rb.z)
        OUTK(c8, (float)dd3.y, sw7, bb.w, rb.w)

        // write back own column (frozen z-halo halves preserved in e0/e4)
        e0 = pkrtz(z0f, c1); e1 = pkrtz(c2, c3); e2 = pkrtz(c4, c5);
        e3 = pkrtz(c6, c7); e4 = pkrtz(c8, z9f);
        bp[55] = e0; bp[56] = e1; bp[57] = e2; bp[58] = e3; bp[59] = e4;

        MEMFENCE();  // stores stay above next iteration's reads (no LICM hoist)

        // interior sums for next iteration's stats (DPP chain overlaps writes)
        float sp = ((c1 + c2) + (c3 + c4)) + ((c5 + c6) + (c7 + c8));
        float qp = ((c1*c1 + c2*c2) + (c3*c3 + c4*c4)) +
                   ((c5*c5 + c6*c6) + (c7*c7 + c8*c8));
        Si = bcast63(wave_sum(sp));
        Qi = bcast63(wave_sum(qp));
    }

    float* yp = Y + ((size_t)batch << 18) + ofs;
    *(float4*)(yp)     = make_float4(c1, c2, c3, c4);
    *(float4*)(yp + 4) = make_float4(c5, c6, c7, c8);
}

extern "C" void kernel_launch(void* const* d_in, const int* in_sizes, int n_in,
                              void* d_out, int out_size, void* d_ws, size_t ws_size,
                              hipStream_t stream) {
    const float* W = (const float*)d_in[0];   // (27,64,64,64)
    const float* B = (const float*)d_in[1];   // (64,64,64)
    const float* R = (const float*)d_in[2];   // (64,64,64)
    const float* X = (const float*)d_in[3];   // (16,64,64,64)
    float* Y = (float*)d_out;

    int n_batch = in_sizes[3] >> 18;          // 64^3 per sample
    dim3 grid(512 * n_batch), block(64);
    hipLaunchKernelGGL(gridnet_kernel, grid, block, 0, stream, W, B, R, X, Y, n_batch);
}

// Round 3
// 221.540 us; speedup vs baseline: 1.0462x; 1.0462x over previous
//
#include <hip/hip_runtime.h>

typedef _Float16 h2 __attribute__((ext_vector_type(2)));

// ---- DPP wave-64 inclusive sum (VALU pipe): full sum lands in lane 63 ----
template <int CTRL>
__device__ __forceinline__ float dpp_stage(float v) {
    int x = __builtin_amdgcn_update_dpp(0, __float_as_int(v), CTRL, 0xf, 0xf, true);
    return v + __int_as_float(x);
}
__device__ __forceinline__ float wave_sum(float v) {
    v = dpp_stage<0x111>(v);  // row_shr:1
    v = dpp_stage<0x112>(v);  // row_shr:2
    v = dpp_stage<0x114>(v);  // row_shr:4
    v = dpp_stage<0x118>(v);  // row_shr:8
    v = dpp_stage<0x142>(v);  // row_bcast:15
    v = dpp_stage<0x143>(v);  // row_bcast:31
    return v;                 // lane 63 holds the full sum
}
__device__ __forceinline__ float bcast63(float v) {
    return __int_as_float(__builtin_amdgcn_readlane(__float_as_int(v), 63));
}
__device__ __forceinline__ h2 mid2(h2 lo, h2 hi) {
    // (lo.y, hi.x) in one whole-register op: v_alignbit_b32
    int r = __builtin_amdgcn_alignbit(__builtin_bit_cast(int, hi),
                                      __builtin_bit_cast(int, lo), 16);
    return __builtin_bit_cast(h2, r);
}
__device__ __forceinline__ h2 pkrtz(float a, float b) {
    return __builtin_bit_cast(h2, __builtin_amdgcn_cvt_pkrtz(a, b));
}

// Compiler-level memory fence (emits nothing): pins LDS load/store program
// order so the single-wave no-barrier scheme is safe against LICM/reordering
// (round-1 stale-neighbor bug). SSA values in registers are unaffected.
#define MEMFENCE() asm volatile("" ::: "memory")

// 27 taps x 4 z-pairs as NAMED h2 SSA values (w0a..w26d): guaranteed register
// residency. Round 2's h2 w[27][4] array was demoted to scratch (VGPR=88 <
// 108 needed; +9MB WRITE_SIZE of spill traffic; VALUBusy 67%->20%).
#define R27(M) M(0) M(1) M(2) M(3) M(4) M(5) M(6) M(7) M(8) M(9) M(10) M(11) \
    M(12) M(13) M(14) M(15) M(16) M(17) M(18) M(19) M(20) M(21) M(22) M(23)  \
    M(24) M(25) M(26)

#define LOADW(T)                                                               \
    h2 w##T##a, w##T##b, w##T##c, w##T##d;                                     \
    {                                                                          \
        const float* wp = W + ((size_t)(T) << 18) + ofs;                       \
        float4 fa = *(const float4*)(wp);                                      \
        float4 fb = *(const float4*)(wp + 4);                                  \
        w##T##a = pkrtz(fa.x, fa.y); w##T##b = pkrtz(fa.z, fa.w);              \
        w##T##c = pkrtz(fb.x, fb.y); w##T##d = pkrtz(fb.z, fb.w);              \
        sw0 += fa.x; sw1 += fa.y; sw2 += fa.z; sw3 += fa.w;                    \
        sw4 += fb.x; sw5 += fb.y; sw6 += fb.z; sw7 += fb.w;                    \
    }

// one window column at h2-offset O (= 5*(10*dx+dy)), taps T0,T1,T2 (literals):
// 5 LDS dword reads from ONE base VGPR via offset immediates, 4 alignbit,
// 12 v_pk_fma_f16 covering all 4 output z-pairs of this thread.
#define COLT(O, T0, T1, T2) {                                                  \
    h2 D0 = bp[(O) + 0], D1 = bp[(O) + 1], D2 = bp[(O) + 2],                   \
       D3 = bp[(O) + 3], D4 = bp[(O) + 4];                                     \
    h2 M0 = mid2(D0, D1), M1 = mid2(D1, D2), M2 = mid2(D2, D3),                \
       M3 = mid2(D3, D4);                                                      \
    dd0 = __builtin_elementwise_fma(D0, w##T0##a, dd0);                        \
    dd1 = __builtin_elementwise_fma(D1, w##T0##b, dd1);                        \
    dd2 = __builtin_elementwise_fma(D2, w##T0##c, dd2);                        \
    dd3 = __builtin_elementwise_fma(D3, w##T0##d, dd3);                        \
    dd0 = __builtin_elementwise_fma(M0, w##T1##a, dd0);                        \
    dd1 = __builtin_elementwise_fma(M1, w##T1##b, dd1);                        \
    dd2 = __builtin_elementwise_fma(M2, w##T1##c, dd2);                        \
    dd3 = __builtin_elementwise_fma(M3, w##T1##d, dd3);                        \
    dd0 = __builtin_elementwise_fma(D1, w##T2##a, dd0);                        \
    dd1 = __builtin_elementwise_fma(D2, w##T2##b, dd1);                        \
    dd2 = __builtin_elementwise_fma(D3, w##T2##c, dd2);                        \
    dd3 = __builtin_elementwise_fma(D4, w##T2##d, dd3); }

// normalized-dot correction + bias + silu + residual for one output
#define OUTK(CK, DDF, SWK, BK, RK) {                                           \
    float u = fmaf(fmaf(SWK, nmean, DDF), istd, BK);                           \
    CK += RK * (u * __builtin_amdgcn_rcpf(1.f + __expf(-u))); }

__global__ __launch_bounds__(256, 2)
void gridnet_kernel(const float* __restrict__ W,
                    const float* __restrict__ Bias,
                    const float* __restrict__ Rs,
                    const float* __restrict__ X,
                    float* __restrict__ Y,
                    int n_batch)
{
    // 4 INDEPENDENT waves per workgroup, each owning a private 2 KB region and
    // its own logical block (same spatial tile, 4 consecutive batches -> W
    // cache lines shared in L1). No inter-wave communication => zero barriers.
    __shared__ __align__(16) h2 buf[4][500];

    const int tid  = threadIdx.x;
    const int wave = tid >> 6;
    const int lane = tid & 63;
    const int lx   = lane >> 3;     // 0..7
    const int ly   = lane & 7;

    // chunked XCD swizzle at workgroup level; waves take 4 consecutive logical
    // blocks (batch-fast) so weight-sharers stay together on one XCD.
    const int nwg = (int)gridDim.x;           // 128*n_batch, divisible by 8
    const int b0  = (int)blockIdx.x;
    const int bid4 = (b0 & 7) * (nwg >> 3) + (b0 >> 3);
    const int lbid = bid4 * 4 + wave;

    const int r     = lbid / n_batch;         // spatial block 0..511
    const int batch = lbid - r * n_batch;
    const int gm0 = (r >> 6) << 3;
    const int gn0 = ((r >> 3) & 7) << 3;
    const int gk0 = (r & 7) << 3;

    const float* xb = X + ((size_t)batch << 18);
    h2* const wbuf = buf[wave];

    // -------- stage: each lane packs 1-2 whole z-columns; stats on rounded --
    float s_all = 0.f, q_all = 0.f, s_int = 0.f, q_int = 0.f;
    #pragma unroll 1
    for (int c = lane; c < 100; c += 64) {
        int x = c / 10, y = c - (c / 10) * 10;   // padded coords 0..9
        int m = gm0 + x - 1, n = gn0 + y - 1;
        bool row_ok = ((unsigned)m < 64u) & ((unsigned)n < 64u);
        float4 fa = {0.f, 0.f, 0.f, 0.f}, fb = {0.f, 0.f, 0.f, 0.f};
        float vz0 = 0.f, vz9 = 0.f;
        if (row_ok) {
            const float* rp = xb + (m * 4096 + n * 64);
            fa = *(const float4*)(rp + gk0);          // z = 1..4
            fb = *(const float4*)(rp + gk0 + 4);      // z = 5..8
            if (gk0 > 0)  vz0 = rp[gk0 - 1];          // uniform branches
            if (gk0 < 56) vz9 = rp[gk0 + 8];
        }
        h2 d0 = pkrtz(vz0, fa.x), d1 = pkrtz(fa.y, fa.z), d2 = pkrtz(fa.w, fb.x),
           d3 = pkrtz(fb.y, fb.z), d4 = pkrtz(fb.w, vz9);
        wbuf[c * 5 + 0] = d0; wbuf[c * 5 + 1] = d1; wbuf[c * 5 + 2] = d2;
        wbuf[c * 5 + 3] = d3; wbuf[c * 5 + 4] = d4;
        // stats over the f16-rounded values the dot will see
        float t0 = (float)d0.x, t1 = (float)d0.y, t2 = (float)d1.x,
              t3 = (float)d1.y, t4 = (float)d2.x, t5 = (float)d2.y,
              t6 = (float)d3.x, t7 = (float)d3.y, t8 = (float)d4.x,
              t9 = (float)d4.y;
        float s8 = t1 + t2 + t3 + t4 + t5 + t6 + t7 + t8;
        float q8 = t1*t1 + t2*t2 + t3*t3 + t4*t4 + t5*t5 + t6*t6 + t7*t7 + t8*t8;
        s_all += s8 + t0 + t9;
        q_all += q8 + t0*t0 + t9*t9;
        bool inter = ((unsigned)(x - 1) < 8u) & ((unsigned)(y - 1) < 8u);
        if (inter) { s_int += s8; q_int += q8; }
    }
    MEMFENCE();   // staging writes stay above everything below

    // -------- per-thread params: 27 taps x 8 k as 108 named h2 registers ----
    const int gm = gm0 + lx, gn = gn0 + ly;
    const size_t ofs = ((size_t)gm << 12) + (gn << 6) + gk0;
    float sw0=0.f, sw1=0.f, sw2=0.f, sw3=0.f, sw4=0.f, sw5=0.f, sw6=0.f, sw7=0.f;
    R27(LOADW)
    float4 ba = *(const float4*)(Bias + ofs), bb = *(const float4*)(Bias + ofs + 4);
    float4 ra = *(const float4*)(Rs + ofs),   rb = *(const float4*)(Rs + ofs + 4);

    // -------- one-time block stats: DPP + readlane only (per-wave) ----------
    float S_all = bcast63(wave_sum(s_all));
    float Q_all = bcast63(wave_sum(q_all));
    float Si    = bcast63(wave_sum(s_int));
    float Qi    = bcast63(wave_sum(q_int));
    const float halo_s = S_all - Si;
    const float halo_q = Q_all - Qi;

    // -------- own column initial state (rounded values from LDS) ------------
    h2* bp = &wbuf[5 * (lx * 10 + ly)];    // window corner; own col = +55 dwords
    h2 e0 = bp[55], e1 = bp[56], e2 = bp[57], e3 = bp[58], e4 = bp[59];
    float z0f = (float)e0.x, z9f = (float)e4.y;       // frozen z-halo halves
    float c1 = (float)e0.y, c2 = (float)e1.x, c3 = (float)e1.y, c4 = (float)e2.x,
          c5 = (float)e2.y, c6 = (float)e3.x, c7 = (float)e3.y, c8 = (float)e4.x;

    const float inv_n = 1.0f / 1000.0f;

    #pragma unroll 1
    for (int it = 0; it < 8; ++it) {
        float mean  = (halo_s + Si) * inv_n;
        float qmean = (halo_q + Qi) * inv_n;
        float istd  = rsqrtf(qmean - mean * mean + 1e-5f);
        float nmean = -mean;

        h2 dd0 = { (_Float16)0.f, (_Float16)0.f };
        h2 dd1 = dd0, dd2 = dd0, dd3 = dd0;
        COLT(0,   0,  1,  2)
        COLT(5,   3,  4,  5)
        COLT(10,  6,  7,  8)
        COLT(50,  9, 10, 11)
        COLT(55, 12, 13, 14)
        COLT(60, 15, 16, 17)
        COLT(100, 18, 19, 20)
        COLT(105, 21, 22, 23)
        COLT(110, 24, 25, 26)

        MEMFENCE();  // all 27 column reads issue before the stores below

        OUTK(c1, (float)dd0.x, sw0, ba.x, ra.x)
        OUTK(c2, (float)dd0.y, sw1, ba.y, ra.y)
        OUTK(c3, (float)dd1.x, sw2, ba.z, ra.z)
        OUTK(c4, (float)dd1.y, sw3, ba.w, ra.w)
        OUTK(c5, (float)dd2.x, sw4, bb.x, rb.x)
        OUTK(c6, (float)dd2.y, sw5, bb.y, rb.y)
        OUTK(c7, (float)dd3.x, sw6, bb.z, rb.z)
        OUTK(c8, (float)dd3.y, sw7, bb.w, rb.w)

        // write back own column (frozen z-halo halves preserved)
        e0 = pkrtz(z0f, c1); e1 = pkrtz(c2, c3); e2 = pkrtz(c4, c5);
        e3 = pkrtz(c6, c7); e4 = pkrtz(c8, z9f);
        bp[55] = e0; bp[56] = e1; bp[57] = e2; bp[58] = e3; bp[59] = e4;

        MEMFENCE();  // stores stay above next iteration's reads (no LICM hoist)

        // interior sums for next iteration's stats (DPP chain overlaps writes)
        float sp = ((c1 + c2) + (c3 + c4)) + ((c5 + c6) + (c7 + c8));
        float qp = ((c1*c1 + c2*c2) + (c3*c3 + c4*c4)) +
                   ((c5*c5 + c6*c6) + (c7*c7 + c8*c8));
        Si = bcast63(wave_sum(sp));
        Qi = bcast63(wave_sum(qp));
    }

    float* yp = Y + ((size_t)batch << 18) + ofs;
    *(float4*)(yp)     = make_float4(c1, c2, c3, c4);
    *(float4*)(yp + 4) = make_float4(c5, c6, c7, c8);
}

extern "C" void kernel_launch(void* const* d_in, const int* in_sizes, int n_in,
                              void* d_out, int out_size, void* d_ws, size_t ws_size,
                              hipStream_t stream) {
    const float* W = (const float*)d_in[0];   // (27,64,64,64)
    const float* B = (const float*)d_in[1];   // (64,64,64)
    const float* R = (const float*)d_in[2];   // (64,64,64)
    const float* X = (const float*)d_in[3];   // (16,64,64,64)
    float* Y = (float*)d_out;

    int n_batch = in_sizes[3] >> 18;          // 64^3 per sample
    dim3 grid(128 * n_batch), block(256);     // 4 logical blocks per workgroup
    hipLaunchKernelGGL(gridnet_kernel, grid, block, 0, stream, W, B, R, X, Y, n_batch);
}

// Round 4
// 188.999 us; speedup vs baseline: 1.2263x; 1.1722x over previous
//
#include <hip/hip_runtime.h>

typedef _Float16 h2 __attribute__((ext_vector_type(2)));

#define COLH 10   // halves per z-column; column stride = 5 dwords (odd -> bank spread)

// ---- DPP wave-64 sum (VALU pipe, not LDS pipe): result valid in lane 63 ----
template <int CTRL>
__device__ __forceinline__ float dpp_stage(float v) {
    int x = __builtin_amdgcn_update_dpp(0, __float_as_int(v), CTRL, 0xf, 0xf, true);
    return v + __int_as_float(x);
}
__device__ __forceinline__ float wave_sum(float v) {
    v = dpp_stage<0x111>(v);  // row_shr:1
    v = dpp_stage<0x112>(v);  // row_shr:2
    v = dpp_stage<0x114>(v);  // row_shr:4
    v = dpp_stage<0x118>(v);  // row_shr:8
    v = dpp_stage<0x142>(v);  // row_bcast:15
    v = dpp_stage<0x143>(v);  // row_bcast:31
    return v;                 // lane 63 holds the full sum
}

#define RFL(x) __int_as_float(__builtin_amdgcn_readfirstlane(__float_as_int(x)))

__device__ __forceinline__ h2 mid2(h2 lo, h2 hi) {
    // (lo.y, hi.x) as one whole-register op: v_alignbit_b32
    int r = __builtin_amdgcn_alignbit(__builtin_bit_cast(int, hi),
                                      __builtin_bit_cast(int, lo), 16);
    return __builtin_bit_cast(h2, r);
}

// ---- 27 taps as named half2 (out0,out1) SSA values: 27 VGPRs, register-resident ----
#define R27(M) M(0) M(1) M(2) M(3) M(4) M(5) M(6) M(7) M(8) M(9) M(10) M(11) \
    M(12) M(13) M(14) M(15) M(16) M(17) M(18) M(19) M(20) M(21) M(22) M(23)  \
    M(24) M(25) M(26)
#define R9L(M) M(0) M(1) M(2) M(3) M(4) M(5) M(6) M(7) M(8)

#define LOADW(T) float2 f##T = *(const float2*)(W + ((size_t)(T) << 18) + ofs); \
                 h2 w##T = { (_Float16)f##T.x, (_Float16)f##T.y };              \
                 sw0 += (float)w##T.x; sw1 += (float)w##T.y;

// one line L: 1 ds_read2_b32 + 1 alignbit + 3 v_pk_fma_f16 (NO scalar half extracts)
//   dd.x += v[2h+k]*wA.. taps (3L,3L+1,3L+2); dd = (d_out0, d_out1)
#define LINE(L, WA, WB, WC) {                                                 \
    const h2 v0 = bp[(((L) / 3) * 10 + (L) % 3) * 5];                         \
    const h2 v1 = bp[(((L) / 3) * 10 + (L) % 3) * 5 + 1];                     \
    const h2 vm = mid2(v0, v1);                                               \
    dd = __builtin_elementwise_fma(v0, WA, dd);                               \
    dd = __builtin_elementwise_fma(vm, WB, dd);                               \
    dd = __builtin_elementwise_fma(v1, WC, dd);  }

// one inner iteration: read SRC, write DST (ping-pong -> single barrier)
#define ITER(SRC, DST, RED) {                                                 \
    const h2* bp = (const h2*)&SRC[base_h];                                   \
    float mean = (halo_s + Si) * inv_n;                                       \
    float istd = rsqrtf((halo_q + Qi) * inv_n - mean * mean + 1e-5f);         \
    h2 dd = { (_Float16)0.f, (_Float16)0.f };                                 \
    LINE(0, w0,  w1,  w2)                                                     \
    LINE(1, w3,  w4,  w5)                                                     \
    LINE(2, w6,  w7,  w8)                                                     \
    LINE(3, w9,  w10, w11)                                                    \
    LINE(4, w12, w13, w14)                                                    \
    LINE(5, w15, w16, w17)                                                    \
    LINE(6, w18, w19, w20)                                                    \
    LINE(7, w21, w22, w23)                                                    \
    LINE(8, w24, w25, w26)                                                    \
    float u0 = ((float)dd.x - mean * sw0) * istd + bias0;                     \
    float u1 = ((float)dd.y - mean * sw1) * istd + bias1;                     \
    c0 += rs0 * (u0 * __builtin_amdgcn_rcpf(1.f + __expf(-u0)));              \
    c1 += rs1 * (u1 * __builtin_amdgcn_rcpf(1.f + __expf(-u1)));              \
    DST[ipc]     = (_Float16)c0;                                              \
    DST[ipc + 1] = (_Float16)c1;                                              \
    float b0 = wave_sum(c0 + c1);                                             \
    float b1 = wave_sum(c0 * c0 + c1 * c1);                                   \
    if (lane == 63) RED[wave] = make_float2(b0, b1);                          \
    __syncthreads();                                                          \
    Si = RFL(RED[0].x + RED[1].x + RED[2].x + RED[3].x);                      \
    Qi = RFL(RED[0].y + RED[1].y + RED[2].y + RED[3].y); }

__global__ __launch_bounds__(256)
void gridnet_kernel(const float* __restrict__ W,
                    const float* __restrict__ Bias,
                    const float* __restrict__ Rs,
                    const float* __restrict__ X,
                    float* __restrict__ Y,
                    int n_batch)
{
    __shared__ __align__(16) _Float16 buf0[100 * COLH];   // 2 KB each
    __shared__ __align__(16) _Float16 buf1[100 * COLH];
    __shared__ float4 red4[4];
    __shared__ float2 redA[4], redB[4];

    const int tid  = threadIdx.x;
    const int h    = tid & 3;            // z-quarter: outputs z = 2h, 2h+1 (block-local)
    const int ly   = (tid >> 2) & 7;
    const int lx   = tid >> 5;
    const int wave = tid >> 6;
    const int lane = tid & 63;

    // chunked XCD swizzle (validated round 3: FETCH 127MB -> 24.9MB): XCD =
    // b0%8 serves a contiguous 1/8 chunk of logical bids, so all 16
    // batch-sharers of a spatial tile hit the same XCD's L2 for W.
    // nwg = 512*n_batch, divisible by 8 -> bijective.
    const int nwg = (int)gridDim.x;
    const int b0  = (int)blockIdx.x;
    const int bid = (b0 & 7) * (nwg >> 3) + (b0 >> 3);

    const int r     = bid / n_batch;     // spatial block 0..511
    const int batch = bid - r * n_batch; // batch-fast: 16 weight-sharers adjacent
    const int gm0 = (r >> 6) << 3;
    const int gn0 = ((r >> 3) & 7) << 3;
    const int gk0 = (r & 7) << 3;

    const float* xb = X + ((size_t)batch << 18);

    // ---- stage 10x10x10 block (zero halo) into BOTH f16 buffers; sums on the fly ----
    float s_all = 0.f, q_all = 0.f, s_int = 0.f, q_int = 0.f;
    for (int i = tid; i < 1000; i += 256) {
        int ix = i / 100;
        int rem = i - ix * 100;
        int iy = rem / 10;
        int iz = rem - iy * 10;
        int m = gm0 + ix - 1, n = gn0 + iy - 1, k = gk0 + iz - 1;
        float v = 0.f;
        if ((unsigned)m < 64u && (unsigned)n < 64u && (unsigned)k < 64u)
            v = xb[(m << 12) + (n << 6) + k];
        _Float16 hv = (_Float16)v;
        int a = (ix * 10 + iy) * COLH + iz;
        buf0[a] = hv;
        buf1[a] = hv;                     // frozen halo must exist in both buffers
        float vf = (float)hv;             // stats over the values the dot will see
        s_all += vf;
        q_all += vf * vf;
        bool interior = ((unsigned)(ix - 1) < 8u) & ((unsigned)(iy - 1) < 8u) &
                        ((unsigned)(iz - 1) < 8u);
        if (interior) { s_int += vf; q_int += vf * vf; }
    }

    // ---- per-thread params: 27 taps x 2 z as half2, register-resident ----
    const int gm = gm0 + lx, gn = gn0 + ly, gk = gk0 + 2 * h;
    const size_t ofs = ((size_t)gm << 12) + (gn << 6) + gk;

    float sw0 = 0.f, sw1 = 0.f;
    R27(LOADW)
    const float2 bf = *(const float2*)(Bias + ofs);
    const float2 rf = *(const float2*)(Rs + ofs);
    const float bias0 = bf.x, bias1 = bf.y;
    const float rs0 = rf.x, rs1 = rf.y;

    __syncthreads();

    // loop-invariant LDS geometry: window base (even half -> h2-aligned), write slot
    const int base_h = (lx * 10 + ly) * COLH + 2 * h;
    const int ipc    = ((lx + 1) * 10 + (ly + 1)) * COLH + (2 * h + 1);
    float c0 = (float)buf0[ipc];
    float c1 = (float)buf0[ipc + 1];

    // ---- one-time reduction: total + interior sums -> frozen halo sums ----
    float a0 = wave_sum(s_all);
    float a1 = wave_sum(q_all);
    float a2 = wave_sum(s_int);
    float a3 = wave_sum(q_int);
    if (lane == 63) red4[wave] = make_float4(a0, a1, a2, a3);
    __syncthreads();
    float S_all = 0.f, Q_all = 0.f, Si = 0.f, Qi = 0.f;
    #pragma unroll
    for (int wv = 0; wv < 4; ++wv) {
        float4 t4 = red4[wv];
        S_all += t4.x; Q_all += t4.y; Si += t4.z; Qi += t4.w;
    }
    const float halo_s = RFL(S_all - Si);
    const float halo_q = RFL(Q_all - Qi);
    Si = RFL(Si);
    Qi = RFL(Qi);

    const float inv_n = 1.0f / 1000.0f;

    // 8 iterations = 4 ping-pong pairs; one barrier per iteration
    #pragma unroll 1
    for (int it = 0; it < 4; ++it) {
        ITER(buf0, buf1, redA)
        ITER(buf1, buf0, redB)
    }

    *(float2*)(Y + ((size_t)batch << 18) + ofs) = make_float2(c0, c1);
}

extern "C" void kernel_launch(void* const* d_in, const int* in_sizes, int n_in,
                              void* d_out, int out_size, void* d_ws, size_t ws_size,
                              hipStream_t stream) {
    const float* W = (const float*)d_in[0];   // (27,64,64,64)
    const float* B = (const float*)d_in[1];   // (64,64,64)
    const float* R = (const float*)d_in[2];   // (64,64,64)
    const float* X = (const float*)d_in[3];   // (16,64,64,64)
    float* Y = (float*)d_out;

    int n_batch = in_sizes[3] >> 18;          // 64^3 per sample
    dim3 grid(512 * n_batch), block(256);
    hipLaunchKernelGGL(gridnet_kernel, grid, block, 0, stream, W, B, R, X, Y, n_batch);
}

// Round 5
// 154.195 us; speedup vs baseline: 1.5031x; 1.2257x over previous
//
#include <hip/hip_runtime.h>

typedef _Float16 h2 __attribute__((ext_vector_type(2)));

#define COLH 10   // halves per z-column; column stride = 5 dwords (odd -> bank spread)

// ---- DPP wave-64 sum (VALU pipe, not LDS pipe): result valid in lane 63 ----
template <int CTRL>
__device__ __forceinline__ float dpp_stage(float v) {
    int x = __builtin_amdgcn_update_dpp(0, __float_as_int(v), CTRL, 0xf, 0xf, true);
    return v + __int_as_float(x);
}
__device__ __forceinline__ float wave_sum(float v) {
    v = dpp_stage<0x111>(v);  // row_shr:1
    v = dpp_stage<0x112>(v);  // row_shr:2
    v = dpp_stage<0x114>(v);  // row_shr:4
    v = dpp_stage<0x118>(v);  // row_shr:8
    v = dpp_stage<0x142>(v);  // row_bcast:15
    v = dpp_stage<0x143>(v);  // row_bcast:31
    return v;                 // lane 63 holds the full sum
}

#define RFL(x) __int_as_float(__builtin_amdgcn_readfirstlane(__float_as_int(x)))

__device__ __forceinline__ h2 mid2(h2 lo, h2 hi) {
    // (lo.y, hi.x) as one whole-register op: v_alignbit_b32
    int r = __builtin_amdgcn_alignbit(__builtin_bit_cast(int, hi),
                                      __builtin_bit_cast(int, lo), 16);
    return __builtin_bit_cast(h2, r);
}

// ---- 27 taps as named half2 SSA values: 27 VGPRs, register-resident,
// SHARED by both batches of the pair (weights are spatial-only) ----
#define R27(M) M(0) M(1) M(2) M(3) M(4) M(5) M(6) M(7) M(8) M(9) M(10) M(11) \
    M(12) M(13) M(14) M(15) M(16) M(17) M(18) M(19) M(20) M(21) M(22) M(23)  \
    M(24) M(25) M(26)

#define LOADW(T) float2 f##T = *(const float2*)(W + ((size_t)(T) << 18) + ofs); \
                 h2 w##T = { (_Float16)f##T.x, (_Float16)f##T.y };              \
                 sw0 += (float)w##T.x; sw1 += (float)w##T.y;

// one line L for one batch: 2 LDS dword reads + 1 alignbit + 3 v_pk_fma_f16
#define LINE(BP, DD, L, WA, WB, WC) {                                         \
    const h2 v0 = BP[(((L) / 3) * 10 + (L) % 3) * 5];                         \
    const h2 v1 = BP[(((L) / 3) * 10 + (L) % 3) * 5 + 1];                     \
    const h2 vm = mid2(v0, v1);                                               \
    DD = __builtin_elementwise_fma(v0, WA, DD);                               \
    DD = __builtin_elementwise_fma(vm, WB, DD);                               \
    DD = __builtin_elementwise_fma(v1, WC, DD);  }

#define DOT9(BP, DD)                                                          \
    LINE(BP, DD, 0, w0,  w1,  w2)                                             \
    LINE(BP, DD, 1, w3,  w4,  w5)                                             \
    LINE(BP, DD, 2, w6,  w7,  w8)                                             \
    LINE(BP, DD, 3, w9,  w10, w11)                                            \
    LINE(BP, DD, 4, w12, w13, w14)                                            \
    LINE(BP, DD, 5, w15, w16, w17)                                            \
    LINE(BP, DD, 6, w18, w19, w20)                                            \
    LINE(BP, DD, 7, w21, w22, w23)                                            \
    LINE(BP, DD, 8, w24, w25, w26)

// norm + bias + silu + residual + LDS writeback for one batch (suffix SFX)
#define EPI(SFX, DST) {                                                       \
    float mean = (halo_s##SFX + Si##SFX) * inv_n;                             \
    float istd = rsqrtf((halo_q##SFX + Qi##SFX) * inv_n - mean*mean + 1e-5f); \
    float u0 = ((float)dd##SFX.x - mean * sw0) * istd + bias0;                \
    float u1 = ((float)dd##SFX.y - mean * sw1) * istd + bias1;                \
    c0##SFX += rs0 * (u0 * __builtin_amdgcn_rcpf(1.f + __expf(-u0)));         \
    c1##SFX += rs1 * (u1 * __builtin_amdgcn_rcpf(1.f + __expf(-u1)));         \
    DST[ipc]     = (_Float16)c0##SFX;                                         \
    DST[ipc + 1] = (_Float16)c1##SFX;  }

// one inner iteration for BOTH batches: two independent dot/epilogue/DPP
// chains interleave (ILP fills each chain's latency); ONE barrier + ONE
// reduction roundtrip serves both.
#define ITERPAIR(SA, DA, SB, DB, RED) {                                       \
    const h2* bpA = (const h2*)&SA[base_h];                                   \
    const h2* bpB = (const h2*)&SB[base_h];                                   \
    h2 ddA = { (_Float16)0.f, (_Float16)0.f };                                \
    h2 ddB = ddA;                                                             \
    DOT9(bpA, ddA)                                                            \
    DOT9(bpB, ddB)                                                            \
    EPI(A, DA)                                                                \
    EPI(B, DB)                                                                \
    float spA = wave_sum(c0A + c1A);                                          \
    float qpA = wave_sum(c0A * c0A + c1A * c1A);                              \
    float spB = wave_sum(c0B + c1B);                                          \
    float qpB = wave_sum(c0B * c0B + c1B * c1B);                              \
    if (lane == 63) { RED[0][wave] = make_float2(spA, qpA);                   \
                      RED[1][wave] = make_float2(spB, qpB); }                 \
    __syncthreads();                                                          \
    SiA = RFL(RED[0][0].x + RED[0][1].x + RED[0][2].x + RED[0][3].x);         \
    QiA = RFL(RED[0][0].y + RED[0][1].y + RED[0][2].y + RED[0][3].y);         \
    SiB = RFL(RED[1][0].x + RED[1][1].x + RED[1][2].x + RED[1][3].x);         \
    QiB = RFL(RED[1][0].y + RED[1][1].y + RED[1][2].y + RED[1][3].y); }

__global__ __launch_bounds__(256)
void gridnet_kernel(const float* __restrict__ W,
                    const float* __restrict__ Bias,
                    const float* __restrict__ Rs,
                    const float* __restrict__ X,
                    float* __restrict__ Y,
                    int n_batch)
{
    __shared__ __align__(16) _Float16 bufA0[100 * COLH];   // 2 KB each
    __shared__ __align__(16) _Float16 bufA1[100 * COLH];
    __shared__ __align__(16) _Float16 bufB0[100 * COLH];
    __shared__ __align__(16) _Float16 bufB1[100 * COLH];
    __shared__ float4 red4[8];          // [0..3] batch A, [4..7] batch B
    __shared__ float2 redP[2][2][4];    // [pingpong][batch][wave]

    const int tid  = threadIdx.x;
    const int h    = tid & 3;            // z-quarter: outputs z = 2h, 2h+1 (block-local)
    const int ly   = (tid >> 2) & 7;
    const int lx   = tid >> 5;
    const int wave = tid >> 6;
    const int lane = tid & 63;

    // NO XCD swizzle: round 4 proved it cuts FETCH 5x but costs 20% time
    // (co-resident blocks lockstep -> phase diversity lost). Natural order
    // keeps co-resident blocks on different tiles -> staging hides under
    // other blocks' compute.
    const int np    = n_batch >> 1;      // batch PAIRS per tile
    const int bid   = blockIdx.x;
    const int r     = bid / np;          // spatial block 0..511
    const int pb    = bid - r * np;      // pair index
    const int batch = 2 * pb;            // batches: batch, batch+1
    const int gm0 = (r >> 6) << 3;
    const int gn0 = ((r >> 3) & 7) << 3;
    const int gk0 = (r & 7) << 3;

    const float* xbA = X + ((size_t)batch << 18);

    // ---- stage 10x10x10 block (zero halo) for BOTH batches; sums on the fly ----
    float sA_all = 0.f, qA_all = 0.f, sA_int = 0.f, qA_int = 0.f;
    float sB_all = 0.f, qB_all = 0.f, sB_int = 0.f, qB_int = 0.f;
    for (int i = tid; i < 1000; i += 256) {
        int ix = i / 100;
        int rem = i - ix * 100;
        int iy = rem / 10;
        int iz = rem - iy * 10;
        int m = gm0 + ix - 1, n = gn0 + iy - 1, k = gk0 + iz - 1;
        float vA = 0.f, vB = 0.f;
        if ((unsigned)m < 64u && (unsigned)n < 64u && (unsigned)k < 64u) {
            const float* p = xbA + (m << 12) + (n << 6) + k;
            vA = p[0];
            vB = p[1 << 18];              // next batch, same spatial offset
        }
        _Float16 hvA = (_Float16)vA;
        _Float16 hvB = (_Float16)vB;
        int a = (ix * 10 + iy) * COLH + iz;
        bufA0[a] = hvA; bufA1[a] = hvA;   // frozen halo must exist in both buffers
        bufB0[a] = hvB; bufB1[a] = hvB;
        float fA = (float)hvA, fB = (float)hvB;
        sA_all += fA; qA_all += fA * fA;
        sB_all += fB; qB_all += fB * fB;
        bool interior = ((unsigned)(ix - 1) < 8u) & ((unsigned)(iy - 1) < 8u) &
                        ((unsigned)(iz - 1) < 8u);
        if (interior) { sA_int += fA; qA_int += fA * fA;
                        sB_int += fB; qB_int += fB * fB; }
    }

    // ---- per-thread params: 27 taps x 2 z as half2 (shared across batches) ----
    const int gm = gm0 + lx, gn = gn0 + ly, gk = gk0 + 2 * h;
    const size_t ofs = ((size_t)gm << 12) + (gn << 6) + gk;

    float sw0 = 0.f, sw1 = 0.f;
    R27(LOADW)
    const float2 bf = *(const float2*)(Bias + ofs);
    const float2 rf = *(const float2*)(Rs + ofs);
    const float bias0 = bf.x, bias1 = bf.y;
    const float rs0 = rf.x, rs1 = rf.y;

    __syncthreads();

    // loop-invariant LDS geometry: window base (even half -> h2-aligned), write slot
    const int base_h = (lx * 10 + ly) * COLH + 2 * h;
    const int ipc    = ((lx + 1) * 10 + (ly + 1)) * COLH + (2 * h + 1);
    float c0A = (float)bufA0[ipc];
    float c1A = (float)bufA0[ipc + 1];
    float c0B = (float)bufB0[ipc];
    float c1B = (float)bufB0[ipc + 1];

    // ---- one-time reduction: total + interior sums -> frozen halo sums ----
    {
        float a0 = wave_sum(sA_all);
        float a1 = wave_sum(qA_all);
        float a2 = wave_sum(sA_int);
        float a3 = wave_sum(qA_int);
        float b0 = wave_sum(sB_all);
        float b1 = wave_sum(qB_all);
        float b2 = wave_sum(sB_int);
        float b3 = wave_sum(qB_int);
        if (lane == 63) {
            red4[wave]     = make_float4(a0, a1, a2, a3);
            red4[4 + wave] = make_float4(b0, b1, b2, b3);
        }
    }
    __syncthreads();
    float SA_all = 0.f, QA_all = 0.f, SiA = 0.f, QiA = 0.f;
    float SB_all = 0.f, QB_all = 0.f, SiB = 0.f, QiB = 0.f;
    #pragma unroll
    for (int wv = 0; wv < 4; ++wv) {
        float4 tA = red4[wv];
        float4 tB = red4[4 + wv];
        SA_all += tA.x; QA_all += tA.y; SiA += tA.z; QiA += tA.w;
        SB_all += tB.x; QB_all += tB.y; SiB += tB.z; QiB += tB.w;
    }
    const float halo_sA = RFL(SA_all - SiA);
    const float halo_qA = RFL(QA_all - QiA);
    const float halo_sB = RFL(SB_all - SiB);
    const float halo_qB = RFL(QB_all - QiB);
    SiA = RFL(SiA); QiA = RFL(QiA);
    SiB = RFL(SiB); QiB = RFL(QiB);

    const float inv_n = 1.0f / 1000.0f;

    // 8 iterations = 4 ping-pong pairs; one barrier per iteration (both batches)
    #pragma unroll 1
    for (int it = 0; it < 4; ++it) {
        ITERPAIR(bufA0, bufA1, bufB0, bufB1, redP[0])
        ITERPAIR(bufA1, bufA0, bufB1, bufB0, redP[1])
    }

    float* yp = Y + ((size_t)batch << 18) + ofs;
    *(float2*)(yp)             = make_float2(c0A, c1A);
    *(float2*)(yp + (1 << 18)) = make_float2(c0B, c1B);
}

extern "C" void kernel_launch(void* const* d_in, const int* in_sizes, int n_in,
                              void* d_out, int out_size, void* d_ws, size_t ws_size,
                              hipStream_t stream) {
    const float* W = (const float*)d_in[0];   // (27,64,64,64)
    const float* B = (const float*)d_in[1];   // (64,64,64)
    const float* R = (const float*)d_in[2];   // (64,64,64)
    const float* X = (const float*)d_in[3];   // (16,64,64,64)
    float* Y = (float*)d_out;

    int n_batch = in_sizes[3] >> 18;          // 64^3 per sample (16, even)
    dim3 grid(512 * (n_batch >> 1)), block(256);
    hipLaunchKernelGGL(gridnet_kernel, grid, block, 0, stream, W, B, R, X, Y, n_batch);
}

// Round 6
// 153.827 us; speedup vs baseline: 1.5067x; 1.0024x over previous
//
#include <hip/hip_runtime.h>

typedef _Float16 h2 __attribute__((ext_vector_type(2)));

#define COLH 10   // halves per z-column; column stride = 5 dwords (odd -> bank spread)

// ---- DPP wave-64 sum (VALU pipe, not LDS pipe): result valid in lane 63 ----
template <int CTRL>
__device__ __forceinline__ float dpp_stage(float v) {
    int x = __builtin_amdgcn_update_dpp(0, __float_as_int(v), CTRL, 0xf, 0xf, true);
    return v + __int_as_float(x);
}
__device__ __forceinline__ float wave_sum(float v) {
    v = dpp_stage<0x111>(v);  // row_shr:1
    v = dpp_stage<0x112>(v);  // row_shr:2
    v = dpp_stage<0x114>(v);  // row_shr:4
    v = dpp_stage<0x118>(v);  // row_shr:8
    v = dpp_stage<0x142>(v);  // row_bcast:15
    v = dpp_stage<0x143>(v);  // row_bcast:31
    return v;                 // lane 63 holds the full sum
}

#define RFL(x) __int_as_float(__builtin_amdgcn_readfirstlane(__float_as_int(x)))

__device__ __forceinline__ h2 mid2(h2 lo, h2 hi) {
    // (lo.y, hi.x) as one whole-register op: v_alignbit_b32
    int r = __builtin_amdgcn_alignbit(__builtin_bit_cast(int, hi),
                                      __builtin_bit_cast(int, lo), 16);
    return __builtin_bit_cast(h2, r);
}

// ---- 27 taps as named half2 SSA values: 27 VGPRs, register-resident,
// SHARED by all 4 batches of the quad (weights are spatial-only) ----
#define R27(M) M(0) M(1) M(2) M(3) M(4) M(5) M(6) M(7) M(8) M(9) M(10) M(11) \
    M(12) M(13) M(14) M(15) M(16) M(17) M(18) M(19) M(20) M(21) M(22) M(23)  \
    M(24) M(25) M(26)

#define LOADW(T) float2 f##T = *(const float2*)(W + ((size_t)(T) << 18) + ofs); \
                 h2 w##T = { (_Float16)f##T.x, (_Float16)f##T.y };              \
                 sw0 += (float)w##T.x; sw1 += (float)w##T.y;

// one line L for one batch: 2 LDS dword reads + 1 alignbit + 3 v_pk_fma_f16
#define LINE(BP, DD, L, WA, WB, WC) {                                         \
    const h2 v0 = BP[(((L) / 3) * 10 + (L) % 3) * 5];                         \
    const h2 v1 = BP[(((L) / 3) * 10 + (L) % 3) * 5 + 1];                     \
    const h2 vm = mid2(v0, v1);                                               \
    DD = __builtin_elementwise_fma(v0, WA, DD);                               \
    DD = __builtin_elementwise_fma(vm, WB, DD);                               \
    DD = __builtin_elementwise_fma(v1, WC, DD);  }

#define DOT9(BP, DD)                                                          \
    LINE(BP, DD, 0, w0,  w1,  w2)                                             \
    LINE(BP, DD, 1, w3,  w4,  w5)                                             \
    LINE(BP, DD, 2, w6,  w7,  w8)                                             \
    LINE(BP, DD, 3, w9,  w10, w11)                                            \
    LINE(BP, DD, 4, w12, w13, w14)                                            \
    LINE(BP, DD, 5, w15, w16, w17)                                            \
    LINE(BP, DD, 6, w18, w19, w20)                                            \
    LINE(BP, DD, 7, w21, w22, w23)                                            \
    LINE(BP, DD, 8, w24, w25, w26)

// norm + bias + silu + residual + LDS writeback for one batch (suffix SFX)
#define EPI(SFX, DST) {                                                       \
    float mean = (halo_s##SFX + Si##SFX) * inv_n;                             \
    float istd = rsqrtf((halo_q##SFX + Qi##SFX) * inv_n - mean*mean + 1e-5f); \
    float u0 = ((float)dd##SFX.x - mean * sw0) * istd + bias0;                \
    float u1 = ((float)dd##SFX.y - mean * sw1) * istd + bias1;                \
    c0##SFX += rs0 * (u0 * __builtin_amdgcn_rcpf(1.f + __expf(-u0)));         \
    c1##SFX += rs1 * (u1 * __builtin_amdgcn_rcpf(1.f + __expf(-u1)));         \
    DST[ipc]     = (_Float16)c0##SFX;                                         \
    DST[ipc + 1] = (_Float16)c1##SFX;  }

// one inner iteration for FOUR batches: four independent dot/epilogue chains
// + eight independent DPP chains interleave (ILP); ONE barrier + ONE
// reduction roundtrip serves all four batches.
#define ITER4(SA, DA, SB, DB, SC, DC, SD, DDst, RED) {                        \
    const h2* bpA = (const h2*)&SA[base_h];                                   \
    const h2* bpB = (const h2*)&SB[base_h];                                   \
    const h2* bpC = (const h2*)&SC[base_h];                                   \
    const h2* bpD = (const h2*)&SD[base_h];                                   \
    h2 ddA = { (_Float16)0.f, (_Float16)0.f };                                \
    h2 ddB = ddA, ddC = ddA, ddD = ddA;                                       \
    DOT9(bpA, ddA)                                                            \
    DOT9(bpB, ddB)                                                            \
    DOT9(bpC, ddC)                                                            \
    DOT9(bpD, ddD)                                                            \
    EPI(A, DA)                                                                \
    EPI(B, DB)                                                                \
    EPI(C, DC)                                                                \
    EPI(D, DDst)                                                              \
    float spA = wave_sum(c0A + c1A);                                          \
    float qpA = wave_sum(c0A * c0A + c1A * c1A);                              \
    float spB = wave_sum(c0B + c1B);                                          \
    float qpB = wave_sum(c0B * c0B + c1B * c1B);                              \
    float spC = wave_sum(c0C + c1C);                                          \
    float qpC = wave_sum(c0C * c0C + c1C * c1C);                              \
    float spD = wave_sum(c0D + c1D);                                          \
    float qpD = wave_sum(c0D * c0D + c1D * c1D);                              \
    if (lane == 63) { RED[0][wave] = make_float2(spA, qpA);                   \
                      RED[1][wave] = make_float2(spB, qpB);                   \
                      RED[2][wave] = make_float2(spC, qpC);                   \
                      RED[3][wave] = make_float2(spD, qpD); }                 \
    __syncthreads();                                                          \
    SiA = RFL(RED[0][0].x + RED[0][1].x + RED[0][2].x + RED[0][3].x);         \
    QiA = RFL(RED[0][0].y + RED[0][1].y + RED[0][2].y + RED[0][3].y);         \
    SiB = RFL(RED[1][0].x + RED[1][1].x + RED[1][2].x + RED[1][3].x);         \
    QiB = RFL(RED[1][0].y + RED[1][1].y + RED[1][2].y + RED[1][3].y);         \
    SiC = RFL(RED[2][0].x + RED[2][1].x + RED[2][2].x + RED[2][3].x);         \
    QiC = RFL(RED[2][0].y + RED[2][1].y + RED[2][2].y + RED[2][3].y);         \
    SiD = RFL(RED[3][0].x + RED[3][1].x + RED[3][2].x + RED[3][3].x);         \
    QiD = RFL(RED[3][0].y + RED[3][1].y + RED[3][2].y + RED[3][3].y); }

__global__ __launch_bounds__(256)
void gridnet_kernel(const float* __restrict__ W,
                    const float* __restrict__ Bias,
                    const float* __restrict__ Rs,
                    const float* __restrict__ X,
                    float* __restrict__ Y,
                    int n_batch)
{
    __shared__ __align__(16) _Float16 bufA0[100 * COLH];   // 2 KB each
    __shared__ __align__(16) _Float16 bufA1[100 * COLH];
    __shared__ __align__(16) _Float16 bufB0[100 * COLH];
    __shared__ __align__(16) _Float16 bufB1[100 * COLH];
    __shared__ __align__(16) _Float16 bufC0[100 * COLH];
    __shared__ __align__(16) _Float16 bufC1[100 * COLH];
    __shared__ __align__(16) _Float16 bufD0[100 * COLH];
    __shared__ __align__(16) _Float16 bufD1[100 * COLH];
    __shared__ float4 red4[4][4];       // [batch][wave]
    __shared__ float2 redP[2][4][4];    // [pingpong][batch][wave]

    const int tid  = threadIdx.x;
    const int h    = tid & 3;            // z-quarter: outputs z = 2h, 2h+1 (block-local)
    const int ly   = (tid >> 2) & 7;
    const int lx   = tid >> 5;
    const int wave = tid >> 6;
    const int lane = tid & 63;

    // NO XCD swizzle (round 4: cuts FETCH 5x but costs 20% time via lockstep).
    const int np    = n_batch >> 2;      // batch QUADS per tile
    const int bid   = blockIdx.x;
    const int r     = bid / np;          // spatial block 0..511
    const int pb    = bid - r * np;      // quad index
    const int batch = 4 * pb;            // batches: batch .. batch+3
    const int gm0 = (r >> 6) << 3;
    const int gn0 = ((r >> 3) & 7) << 3;
    const int gk0 = (r & 7) << 3;

    const float* xbA = X + ((size_t)batch << 18);

    // ---- stage 10x10x10 block (zero halo) for FOUR batches; sums on the fly ----
    float sA_all = 0.f, qA_all = 0.f, sA_int = 0.f, qA_int = 0.f;
    float sB_all = 0.f, qB_all = 0.f, sB_int = 0.f, qB_int = 0.f;
    float sC_all = 0.f, qC_all = 0.f, sC_int = 0.f, qC_int = 0.f;
    float sD_all = 0.f, qD_all = 0.f, sD_int = 0.f, qD_int = 0.f;
    for (int i = tid; i < 1000; i += 256) {
        int ix = i / 100;
        int rem = i - ix * 100;
        int iy = rem / 10;
        int iz = rem - iy * 10;
        int m = gm0 + ix - 1, n = gn0 + iy - 1, k = gk0 + iz - 1;
        float vA = 0.f, vB = 0.f, vC = 0.f, vD = 0.f;
        if ((unsigned)m < 64u && (unsigned)n < 64u && (unsigned)k < 64u) {
            const float* p = xbA + (m << 12) + (n << 6) + k;
            vA = p[0];
            vB = p[1 << 18];
            vC = p[2 << 18];
            vD = p[3 << 18];
        }
        _Float16 hvA = (_Float16)vA, hvB = (_Float16)vB;
        _Float16 hvC = (_Float16)vC, hvD = (_Float16)vD;
        int a = (ix * 10 + iy) * COLH + iz;
        bufA0[a] = hvA; bufA1[a] = hvA;   // frozen halo must exist in both buffers
        bufB0[a] = hvB; bufB1[a] = hvB;
        bufC0[a] = hvC; bufC1[a] = hvC;
        bufD0[a] = hvD; bufD1[a] = hvD;
        float fA = (float)hvA, fB = (float)hvB, fC = (float)hvC, fD = (float)hvD;
        sA_all += fA; qA_all += fA * fA;
        sB_all += fB; qB_all += fB * fB;
        sC_all += fC; qC_all += fC * fC;
        sD_all += fD; qD_all += fD * fD;
        bool interior = ((unsigned)(ix - 1) < 8u) & ((unsigned)(iy - 1) < 8u) &
                        ((unsigned)(iz - 1) < 8u);
        if (interior) { sA_int += fA; qA_int += fA * fA;
                        sB_int += fB; qB_int += fB * fB;
                        sC_int += fC; qC_int += fC * fC;
                        sD_int += fD; qD_int += fD * fD; }
    }

    // one-time reduction NOW (shortens accumulator liveness; 16 independent
    // DPP chains pipeline); visibility covered by the single barrier below.
    {
        float a0 = wave_sum(sA_all), a1 = wave_sum(qA_all);
        float a2 = wave_sum(sA_int), a3 = wave_sum(qA_int);
        float b0 = wave_sum(sB_all), b1 = wave_sum(qB_all);
        float b2 = wave_sum(sB_int), b3 = wave_sum(qB_int);
        float c0 = wave_sum(sC_all), c1 = wave_sum(qC_all);
        float c2 = wave_sum(sC_int), c3 = wave_sum(qC_int);
        float d0 = wave_sum(sD_all), d1 = wave_sum(qD_all);
        float d2 = wave_sum(sD_int), d3 = wave_sum(qD_int);
        if (lane == 63) {
            red4[0][wave] = make_float4(a0, a1, a2, a3);
            red4[1][wave] = make_float4(b0, b1, b2, b3);
            red4[2][wave] = make_float4(c0, c1, c2, c3);
            red4[3][wave] = make_float4(d0, d1, d2, d3);
        }
    }

    // ---- per-thread params: 27 taps x 2 z as half2 (shared across batches) ----
    const int gm = gm0 + lx, gn = gn0 + ly, gk = gk0 + 2 * h;
    const size_t ofs = ((size_t)gm << 12) + (gn << 6) + gk;

    float sw0 = 0.f, sw1 = 0.f;
    R27(LOADW)
    const float2 bf = *(const float2*)(Bias + ofs);
    const float2 rf = *(const float2*)(Rs + ofs);
    const float bias0 = bf.x, bias1 = bf.y;
    const float rs0 = rf.x, rs1 = rf.y;

    __syncthreads();   // staging + red4 visible to all waves

    // loop-invariant LDS geometry: window base (even half -> h2-aligned), write slot
    const int base_h = (lx * 10 + ly) * COLH + 2 * h;
    const int ipc    = ((lx + 1) * 10 + (ly + 1)) * COLH + (2 * h + 1);
    float c0A = (float)bufA0[ipc], c1A = (float)bufA0[ipc + 1];
    float c0B = (float)bufB0[ipc], c1B = (float)bufB0[ipc + 1];
    float c0C = (float)bufC0[ipc], c1C = (float)bufC0[ipc + 1];
    float c0D = (float)bufD0[ipc], c1D = (float)bufD0[ipc + 1];

    float SA_all = 0.f, QA_all = 0.f, SiA = 0.f, QiA = 0.f;
    float SB_all = 0.f, QB_all = 0.f, SiB = 0.f, QiB = 0.f;
    float SC_all = 0.f, QC_all = 0.f, SiC = 0.f, QiC = 0.f;
    float SD_all = 0.f, QD_all = 0.f, SiD = 0.f, QiD = 0.f;
    #pragma unroll
    for (int wv = 0; wv < 4; ++wv) {
        float4 tA = red4[0][wv];
        float4 tB = red4[1][wv];
        float4 tC = red4[2][wv];
        float4 tD = red4[3][wv];
        SA_all += tA.x; QA_all += tA.y; SiA += tA.z; QiA += tA.w;
        SB_all += tB.x; QB_all += tB.y; SiB += tB.z; QiB += tB.w;
        SC_all += tC.x; QC_all += tC.y; SiC += tC.z; QiC += tC.w;
        SD_all += tD.x; QD_all += tD.y; SiD += tD.z; QiD += tD.w;
    }
    const float halo_sA = RFL(SA_all - SiA), halo_qA = RFL(QA_all - QiA);
    const float halo_sB = RFL(SB_all - SiB), halo_qB = RFL(QB_all - QiB);
    const float halo_sC = RFL(SC_all - SiC), halo_qC = RFL(QC_all - QiC);
    const float halo_sD = RFL(SD_all - SiD), halo_qD = RFL(QD_all - QiD);
    SiA = RFL(SiA); QiA = RFL(QiA);
    SiB = RFL(SiB); QiB = RFL(QiB);
    SiC = RFL(SiC); QiC = RFL(QiC);
    SiD = RFL(SiD); QiD = RFL(QiD);

    const float inv_n = 1.0f / 1000.0f;

    // 8 iterations = 4 ping-pong pairs; one barrier per iteration (4 batches)
    #pragma unroll 1
    for (int it = 0; it < 4; ++it) {
        ITER4(bufA0, bufA1, bufB0, bufB1, bufC0, bufC1, bufD0, bufD1, redP[0])
        ITER4(bufA1, bufA0, bufB1, bufB0, bufC1, bufC0, bufD1, bufD0, redP[1])
    }

    float* yp = Y + ((size_t)batch << 18) + ofs;
    *(float2*)(yp)             = make_float2(c0A, c1A);
    *(float2*)(yp + (1 << 18)) = make_float2(c0B, c1B);
    *(float2*)(yp + (2 << 18)) = make_float2(c0C, c1C);
    *(float2*)(yp + (3 << 18)) = make_float2(c0D, c1D);
}

extern "C" void kernel_launch(void* const* d_in, const int* in_sizes, int n_in,
                              void* d_out, int out_size, void* d_ws, size_t ws_size,
                              hipStream_t stream) {
    const float* W = (const float*)d_in[0];   // (27,64,64,64)
    const float* B = (const float*)d_in[1];   // (64,64,64)
    const float* R = (const float*)d_in[2];   // (64,64,64)
    const float* X = (const float*)d_in[3];   // (16,64,64,64)
    float* Y = (float*)d_out;

    int n_batch = in_sizes[3] >> 18;          // 64^3 per sample (16, div by 4)
    dim3 grid(512 * (n_batch >> 2)), block(256);
    hipLaunchKernelGGL(gridnet_kernel, grid, block, 0, stream, W, B, R, X, Y, n_batch);
}